// Round 20
// baseline (203.882 us; speedup 1.0000x reference)
//
#include <hip/hip_runtime.h>

#define N_NODES 100000
#define N_EDGES 1600000
#define IN_CH   165
#define BSHIFT 7
#define NBUCK  ((N_NODES + 127) / 128)   // 782
#define BCAP   3072                       // bucket region capacity (mean 2046, ~20 sigma)
#define PA_BLOCKS 256
#define WSPLIT_BLOCKS 128                 // (128*192 + 64*128) / 256 = 128
#define G1_BLOCKS ((N_NODES + 63) / 64)   // 1563

typedef unsigned short ushort_t;
typedef _Float16 f16;
typedef _Float16 f16x8 __attribute__((ext_vector_type(8)));
typedef _Float16 hfrag8 __attribute__((ext_vector_type(8)));
typedef short bfrag8 __attribute__((ext_vector_type(8)));   // 8 bf16 (4 VGPRs)
typedef float f32x4 __attribute__((ext_vector_type(4)));
typedef float f32x4u __attribute__((ext_vector_type(4), aligned(4)));  // 4B-aligned vector load

// bf16 round-to-nearest-even
__device__ __forceinline__ ushort_t f2bf(float f) {
    unsigned u = __float_as_uint(f);
    unsigned r = (u + 0x7fffu + ((u >> 16) & 1u)) >> 16;
    return (ushort_t)r;
}
__device__ __forceinline__ float bf2f(ushort_t h) {
    return __uint_as_float(((unsigned)h) << 16);
}

// acc += f16(half of pair) * s via v_fma_mix_f32
__device__ __forceinline__ void fmix_lo(float& a, unsigned pair, float s) {
    asm("v_fma_mix_f32 %0, %1, %2, %0 op_sel_hi:[1,0,0]" : "+v"(a) : "v"(pair), "v"(s));
}
__device__ __forceinline__ void fmix_hi(float& a, unsigned pair, float s) {
    asm("v_fma_mix_f32 %0, %1, %2, %0 op_sel:[1,0,0] op_sel_hi:[1,0,0]" : "+v"(a) : "v"(pair), "v"(s));
}
__device__ __forceinline__ void fmix_acc8(float* acc, uint4 v, float s) {
    fmix_lo(acc[0], v.x, s); fmix_hi(acc[1], v.x, s);
    fmix_lo(acc[2], v.y, s); fmix_hi(acc[3], v.y, s);
    fmix_lo(acc[4], v.z, s); fmix_hi(acc[5], v.z, s);
    fmix_lo(acc[6], v.w, s); fmix_hi(acc[7], v.w, s);
}

// ---------------- wsplit (also zeroes bfill) ----------------
// W1 -> bf16 hi/lo [ch][192]; W2 -> fp16 hi/lo [ch][128]
__global__ void wsplit_kernel(const float* __restrict__ W1, const float* __restrict__ W2,
                              ushort_t* __restrict__ wt1h, ushort_t* __restrict__ wt1l,
                              ushort_t* __restrict__ wt2h, ushort_t* __restrict__ wt2l,
                              int* __restrict__ bfill) {
    int i = blockIdx.x * 256 + threadIdx.x;
    if (i < NBUCK) bfill[i] = 0;
    if (i < 128 * 192) {
        int ch = i / 192, k = i - ch * 192;
        float v = (k < IN_CH) ? W1[(size_t)k * 128 + ch] : 0.f;
        ushort_t h = f2bf(v);
        wt1h[i] = h;
        wt1l[i] = f2bf(v - bf2f(h));
    } else if (i < 128 * 192 + 64 * 128) {
        int j = i - 128 * 192;
        int ch = j / 128, k = j - ch * 128;
        float v = W2[(size_t)k * 64 + ch];
        f16 h = (f16)v;
        f16 l = (f16)(v - (float)h);
        wt2h[j] = *(ushort_t*)&h;
        wt2l[j] = *(ushort_t*)&l;
    }
}

// ---------------- bucketAg1: gemm1 (blocks 0..G1-1)  ||  bucketA (rest) ----------
// gemm blocks dispatched FIRST so the long gemm wavefront starts immediately.
// bucketA: coarse scatter into fixed bucket regions tmp[b*BCAP..].
// gemm1: M[n][128] = X[n][165] @ W1 (UNSCALED), split-bf16 3-term MFMA, fp16 out.
//        W staged in LDS (cross-lane dedup, 20.5KB); X A-frags per-lane, float4x2.
__launch_bounds__(256)
__global__ void bucketAg1_kernel(const int* __restrict__ row, const int* __restrict__ col,
                                 int* __restrict__ bfill, unsigned* __restrict__ tmp,
                                 const float* __restrict__ X,
                                 const ushort_t* __restrict__ wth, const ushort_t* __restrict__ wtl,
                                 f16* __restrict__ M, int n_nodes) {
    __shared__ char smem[20480];
    int t = threadIdx.x;
    int lane = t & 63, wid = t >> 6;
    if (blockIdx.x >= G1_BLOCKS) {
        // ---- bucketA ----
        int* lcnt = (int*)smem;                       // NBUCK ints
        int* lcur = ((int*)smem) + NBUCK;             // NBUCK ints (6256 B total)
        int pb_ = blockIdx.x - G1_BLOCKS;
        int e0 = (int)((long)pb_ * N_EDGES / PA_BLOCKS);
        int e1 = (int)((long)(pb_ + 1) * N_EDGES / PA_BLOCKS);
        for (int i = t; i < NBUCK; i += 256) lcnt[i] = 0;
        __syncthreads();
        for (int e = e0 + t; e < e1; e += 256)
            atomicAdd(&lcnt[col[e] >> BSHIFT], 1);
        __syncthreads();
        for (int b = t; b < NBUCK; b += 256) {
            int c = lcnt[b];
            lcur[b] = (c > 0) ? (b * BCAP + atomicAdd(&bfill[b], c)) : 0;
        }
        __syncthreads();
        for (int e = e0 + t; e < e1; e += 256) {
            int cc = col[e];
            int b = cc >> BSHIFT;
            int p = atomicAdd(&lcur[b], 1);
            tmp[p] = ((unsigned)(cc & 127) << 17) | (unsigned)row[e];
        }
        return;
    }
    // ---- gemm1: W in LDS, X per-lane (vectorized) ----
    constexpr int XP = 40;
    ushort_t (*wsh)[XP] = (ushort_t(*)[XP])smem;             // 10240
    ushort_t (*wsl)[XP] = (ushort_t(*)[XP])(smem + 10240);   // 10240

    int bid = blockIdx.x;
    long node0 = (long)bid * 64;
    int r = (int)node0 + wid * 16 + (lane & 15);
    int rr = min(r, n_nodes - 1);
    int q = lane >> 4;
    const float* xrow = X + (size_t)rr * IN_CH;

    f32x4 acc[8];
    #pragma unroll
    for (int ct = 0; ct < 8; ++ct) acc[ct] = (f32x4){0.f, 0.f, 0.f, 0.f};

    bfrag8 wfh[2], wfl[2];
    float a[8];

    auto loadW = [&](int c) {
        int k0 = c * 32;
        #pragma unroll
        for (int i = 0; i < 2; ++i) {
            int idx = t + i * 256;
            int ch = idx >> 2, qq = idx & 3;
            wfh[i] = *(const bfrag8*)&wth[(size_t)ch * 192 + k0 + qq * 8];
            wfl[i] = *(const bfrag8*)&wtl[(size_t)ch * 192 + k0 + qq * 8];
        }
    };
    auto storeW = [&]() {
        #pragma unroll
        for (int i = 0; i < 2; ++i) {
            int idx = t + i * 256;
            int ch = idx >> 2, qq = idx & 3;
            *(bfrag8*)&wsh[ch][qq * 8] = wfh[i];
            *(bfrag8*)&wsl[ch][qq * 8] = wfl[i];
        }
    };
    auto loadX = [&](int c) {
        int k = c * 32 + q * 8;
        if (c < 5) {
            f32x4u u = *(const f32x4u*)&xrow[k];
            f32x4u v = *(const f32x4u*)&xrow[k + 4];
            a[0] = u.x; a[1] = u.y; a[2] = u.z; a[3] = u.w;
            a[4] = v.x; a[5] = v.y; a[6] = v.z; a[7] = v.w;
        } else {
            // chunk 5: k in [160,192); valid only k<165 (quarter 0, elems 0..4)
            #pragma unroll
            for (int i = 0; i < 8; ++i) a[i] = 0.f;
            if (q == 0) {
                f32x4u u = *(const f32x4u*)&xrow[160];
                a[0] = u.x; a[1] = u.y; a[2] = u.z; a[3] = u.w;
                a[4] = xrow[164];
            }
        }
    };

    loadW(0);
    loadX(0);
    #pragma unroll 1
    for (int c = 0; c < 6; ++c) {
        storeW();
        __syncthreads();
        if (c + 1 < 6) loadW(c + 1);
        bfrag8 ah, al;
        #pragma unroll
        for (int i = 0; i < 8; ++i) {
            ushort_t h = (ushort_t)(__float_as_uint(a[i]) >> 16);   // truncation split
            ah[i] = (short)h;
            al[i] = (short)f2bf(a[i] - bf2f(h));
        }
        if (c + 1 < 6) loadX(c + 1);   // prefetch next A under MFMAs
        #pragma unroll
        for (int ct = 0; ct < 8; ++ct) {
            bfrag8 bh = *(const bfrag8*)&wsh[ct * 16 + (lane & 15)][q * 8];
            bfrag8 bl = *(const bfrag8*)&wsl[ct * 16 + (lane & 15)][q * 8];
            acc[ct] = __builtin_amdgcn_mfma_f32_16x16x32_bf16(ah, bh, acc[ct], 0, 0, 0);
            acc[ct] = __builtin_amdgcn_mfma_f32_16x16x32_bf16(ah, bl, acc[ct], 0, 0, 0);
            acc[ct] = __builtin_amdgcn_mfma_f32_16x16x32_bf16(al, bh, acc[ct], 0, 0, 0);
        }
        __syncthreads();
    }

    int nl = wid * 16 + (lane >> 4) * 4;
    #pragma unroll
    for (int ct = 0; ct < 8; ++ct) {
        int ch = ct * 16 + (lane & 15);
        #pragma unroll
        for (int j = 0; j < 4; ++j) {
            long node = node0 + nl + j;
            if (node < n_nodes)
                M[node * 128 + ch] = (f16)acc[ct][j];
        }
    }
}

// ---------------- bucketB: self-sufficient (recount, reduce base, dis/off/srt) ----
__global__ void bucketB_kernel(const unsigned* __restrict__ tmp, const int* __restrict__ bfill,
                               float* __restrict__ dis, int* __restrict__ off,
                               unsigned* __restrict__ srt) {
    __shared__ int lcnt[128];
    __shared__ int wred[4];
    __shared__ int sh[128];
    __shared__ int lcur[128];
    int t = threadIdx.x;
    int lane = t & 63, wid = t >> 6;
    int b = blockIdx.x;
    if (t < 128) lcnt[t] = 0;
    __syncthreads();
    int total = min(bfill[b], BCAP);
    const unsigned* reg = tmp + (size_t)b * BCAP;
    for (int i = t; i < total; i += 256)
        atomicAdd(&lcnt[(reg[i] >> 17) & 127], 1);
    // base = sum_{j<b} bfill[j]   (<=781 ints, L2-hot)
    int s = 0;
    for (int j = t; j < b; j += 256) s += bfill[j];
    #pragma unroll
    for (int o = 32; o > 0; o >>= 1) s += __shfl_xor(s, o);
    if (lane == 0) wred[wid] = s;
    __syncthreads();                       // fences lcnt atomics + wred
    int base = wred[0] + wred[1] + wred[2] + wred[3];
    int myc = 0;
    if (t < 128) {
        myc = lcnt[t];
        int n = (b << BSHIFT) + t;
        if (n < N_NODES) dis[n] = rsqrtf((float)(myc + 1));
        sh[t] = myc;
    }
    __syncthreads();
    for (int o = 1; o < 128; o <<= 1) {
        int x = (t < 128 && t >= o) ? sh[t - o] : 0;
        __syncthreads();
        if (t < 128) sh[t] += x;
        __syncthreads();
    }
    if (t < 128) {
        int excl = sh[t] - myc;
        int n = (b << BSHIFT) + t;
        if (n < N_NODES) off[n] = base + excl;
        lcur[t] = excl;
    }
    if (b == 0 && t == 0) off[N_NODES] = N_EDGES;
    __syncthreads();
    for (int i = t; i < total; i += 256) {
        unsigned e = reg[i];
        int c = (e >> 17) & 127;
        int p = atomicAdd(&lcur[c], 1);
        srt[base + p] = e & 0x1FFFFu;
    }
}

// ---------------- gemm2: M[n][64] = H[n][128] @ W2 (UNSCALED) ----------------
__launch_bounds__(256)
__global__ void gemm2_kernel(const f16* __restrict__ H,
                             const ushort_t* __restrict__ wth, const ushort_t* __restrict__ wtl,
                             f16* __restrict__ M, int n_nodes) {
    constexpr int XP = 40;
    __shared__ ushort_t wsh[64][XP];
    __shared__ ushort_t wsl[64][XP];
    int t = threadIdx.x;
    int l = t & 63, wid = t >> 6;
    long node0 = (long)blockIdx.x * 64;
    int r = (int)node0 + wid * 16 + (l & 15);
    int rr = min(r, n_nodes - 1);
    int q = l >> 4;
    const f16* hrow = H + (size_t)rr * 128;

    f32x4 acc[4];
    #pragma unroll
    for (int ct = 0; ct < 4; ++ct) acc[ct] = (f32x4){0.f, 0.f, 0.f, 0.f};

    bfrag8 wfh, wfl;
    auto loadW = [&](int c) {
        int ch = t >> 2, qq = t & 3;
        wfh = *(const bfrag8*)&wth[(size_t)ch * 128 + c * 32 + qq * 8];
        wfl = *(const bfrag8*)&wtl[(size_t)ch * 128 + c * 32 + qq * 8];
    };
    auto storeW = [&]() {
        int ch = t >> 2, qq = t & 3;
        *(bfrag8*)&wsh[ch][qq * 8] = wfh;
        *(bfrag8*)&wsl[ch][qq * 8] = wfl;
    };

    loadW(0);
    hfrag8 a = *(const hfrag8*)&hrow[q * 8];
    #pragma unroll 1
    for (int c = 0; c < 4; ++c) {
        storeW();
        __syncthreads();
        if (c + 1 < 4) loadW(c + 1);
        hfrag8 acur = a;
        if (c + 1 < 4) a = *(const hfrag8*)&hrow[(c + 1) * 32 + q * 8];
        #pragma unroll
        for (int ct = 0; ct < 4; ++ct) {
            hfrag8 bh = *(const hfrag8*)&wsh[ct * 16 + (l & 15)][q * 8];
            hfrag8 bl = *(const hfrag8*)&wsl[ct * 16 + (l & 15)][q * 8];
            acc[ct] = __builtin_amdgcn_mfma_f32_16x16x32_f16(acur, bh, acc[ct], 0, 0, 0);
            acc[ct] = __builtin_amdgcn_mfma_f32_16x16x32_f16(acur, bl, acc[ct], 0, 0, 0);
        }
        __syncthreads();
    }

    int nl = wid * 16 + (l >> 4) * 4;
    #pragma unroll
    for (int ct = 0; ct < 4; ++ct) {
        int ch = ct * 16 + (l & 15);
        #pragma unroll
        for (int j = 0; j < 4; ++j) {
            long node = node0 + nl + j;
            if (node < n_nodes)
                M[node * 64 + ch] = (f16)acc[ct][j];
        }
    }
}

// ---------------- aggregation layer 1: 128 ch fp16, wave-per-node ----------------
// srt plain src; dis[src] loaded per edge (L2-resident 400 KB); dn from degree.
__global__ void agg1_kernel(const f16* __restrict__ ms, const unsigned* __restrict__ srt,
                            const int* __restrict__ off, const float* __restrict__ dis,
                            const float* __restrict__ b1, f16* __restrict__ h1) {
    int wave = threadIdx.x >> 6;
    int lane = threadIdx.x & 63;
    int n = blockIdx.x * 4 + wave;
    if (n >= N_NODES) return;
    int g = lane >> 4, p = lane & 15;
    const char* msb = (const char*)ms;
    unsigned pb = (unsigned)p * 16;
    int s0 = off[n], s1 = off[n + 1];
    float dn = rsqrtf((float)(s1 - s0) + 1.f);
    float acc[8] = {0.f, 0.f, 0.f, 0.f, 0.f, 0.f, 0.f, 0.f};
    if (g == 0) {   // self row x dn
        uint4 v = *(const uint4*)(msb + (unsigned)n * 256 + pb);
        fmix_acc8(acc, v, dn);
    }
    unsigned sv = (s0 + lane < s1) ? srt[s0 + lane] : 0;
    for (int base = s0; base < s1; base += 64) {
        int nb2 = base + 64;
        unsigned svn = (nb2 + lane < s1) ? srt[nb2 + lane] : 0;
        int cnt_ = min(64, s1 - base);
        int j = 0;
        for (; j + 15 < cnt_; j += 16) {
            unsigned e0 = (unsigned)__shfl((int)sv, j + g);
            unsigned e1 = (unsigned)__shfl((int)sv, j + 4 + g);
            unsigned e2 = (unsigned)__shfl((int)sv, j + 8 + g);
            unsigned e3 = (unsigned)__shfl((int)sv, j + 12 + g);
            uint4 v0 = *(const uint4*)(msb + e0 * 256 + pb);
            uint4 v1 = *(const uint4*)(msb + e1 * 256 + pb);
            uint4 v2 = *(const uint4*)(msb + e2 * 256 + pb);
            uint4 v3 = *(const uint4*)(msb + e3 * 256 + pb);
            float d0 = dis[e0];
            float d1 = dis[e1];
            float d2 = dis[e2];
            float d3 = dis[e3];
            fmix_acc8(acc, v0, d0);
            fmix_acc8(acc, v1, d1);
            fmix_acc8(acc, v2, d2);
            fmix_acc8(acc, v3, d3);
        }
        for (; j < cnt_; j += 4) {
            unsigned e = (unsigned)__shfl((int)sv, j + g);
            float ws = (j + g < cnt_) ? dis[e] : 0.f;
            uint4 v = *(const uint4*)(msb + e * 256 + pb);
            fmix_acc8(acc, v, ws);
        }
        sv = svn;
    }
    #pragma unroll
    for (int i = 0; i < 8; ++i) {
        acc[i] += __shfl_xor(acc[i], 16);
        acc[i] += __shfl_xor(acc[i], 32);
    }
    if (lane < 16) {
        float4 ba = ((const float4*)b1)[lane * 2];
        float4 bb = ((const float4*)b1)[lane * 2 + 1];
        float bv[8] = {ba.x, ba.y, ba.z, ba.w, bb.x, bb.y, bb.z, bb.w};
        f16x8 r;
        #pragma unroll
        for (int i = 0; i < 8; ++i)
            r[i] = (f16)fmaxf(acc[i] * dn + bv[i], 0.f);
        *(f16x8*)(h1 + (size_t)n * 128 + lane * 8) = r;
    }
}

// ---------------- aggregation layer 2 (64 ch fp16) + output GEMM (64 -> 2) ----------------
__global__ void agg2_kernel(const f16* __restrict__ ms, const unsigned* __restrict__ srt,
                            const int* __restrict__ off, const float* __restrict__ dis,
                            const float* __restrict__ b2, const float* __restrict__ Wo,
                            const float* __restrict__ bo, float* __restrict__ out) {
    int wave = threadIdx.x >> 6;
    int lane = threadIdx.x & 63;
    int n = blockIdx.x * 4 + wave;
    if (n >= N_NODES) return;
    int g = lane >> 3, p = lane & 7;
    const char* msb = (const char*)ms;
    unsigned pb = (unsigned)p * 16;
    int s0 = off[n], s1 = off[n + 1];
    float dn = rsqrtf((float)(s1 - s0) + 1.f);
    float acc[8] = {0.f, 0.f, 0.f, 0.f, 0.f, 0.f, 0.f, 0.f};
    if (g == 0) {   // self row x dn
        uint4 v = *(const uint4*)(msb + (unsigned)n * 128 + pb);
        fmix_acc8(acc, v, dn);
    }
    unsigned sv = (s0 + lane < s1) ? srt[s0 + lane] : 0;
    for (int base = s0; base < s1; base += 64) {
        int nb2 = base + 64;
        unsigned svn = (nb2 + lane < s1) ? srt[nb2 + lane] : 0;
        int cnt_ = min(64, s1 - base);
        int j = 0;
        for (; j + 15 < cnt_; j += 16) {
            unsigned e0 = (unsigned)__shfl((int)sv, j + g);
            unsigned e1 = (unsigned)__shfl((int)sv, j + 8 + g);
            uint4 v0 = *(const uint4*)(msb + e0 * 128 + pb);
            uint4 v1 = *(const uint4*)(msb + e1 * 128 + pb);
            float d0 = dis[e0];
            float d1 = dis[e1];
            fmix_acc8(acc, v0, d0);
            fmix_acc8(acc, v1, d1);
        }
        for (; j < cnt_; j += 8) {
            unsigned e = (unsigned)__shfl((int)sv, j + g);
            float ws = (j + g < cnt_) ? dis[e] : 0.f;
            uint4 v = *(const uint4*)(msb + e * 128 + pb);
            fmix_acc8(acc, v, ws);
        }
        sv = svn;
    }
    #pragma unroll
    for (int i = 0; i < 8; ++i) {
        acc[i] += __shfl_xor(acc[i], 8);
        acc[i] += __shfl_xor(acc[i], 16);
        acc[i] += __shfl_xor(acc[i], 32);
    }
    float p0 = 0.f, p1 = 0.f;
    #pragma unroll
    for (int i = 0; i < 8; ++i) {
        int ch = p * 8 + i;
        float hc = fmaxf(acc[i] * dn + b2[ch], 0.f);
        p0 = fmaf(hc, Wo[ch * 2], p0);
        p1 = fmaf(hc, Wo[ch * 2 + 1], p1);
    }
    p0 += __shfl_xor(p0, 1); p1 += __shfl_xor(p1, 1);
    p0 += __shfl_xor(p0, 2); p1 += __shfl_xor(p1, 2);
    p0 += __shfl_xor(p0, 4); p1 += __shfl_xor(p1, 4);
    if (lane == 0) {
        out[(size_t)n * 2]     = p0 + bo[0];
        out[(size_t)n * 2 + 1] = p1 + bo[1];
    }
}

// ---------------- launch ----------------
extern "C" void kernel_launch(void* const* d_in, const int* in_sizes, int n_in,
                              void* d_out, int out_size, void* d_ws, size_t ws_size,
                              hipStream_t stream) {
    const float* x  = (const float*)d_in[0];
    const int*   ei = (const int*)d_in[1];
    const int*   row = ei;
    const int*   col = ei + N_EDGES;
    const float* W1 = (const float*)d_in[2];
    const float* b1 = (const float*)d_in[3];
    const float* W2 = (const float*)d_in[4];
    const float* b2 = (const float*)d_in[5];
    const float* Wo = (const float*)d_in[6];
    const float* bo = (const float*)d_in[7];
    float* out = (float*)d_out;

    char* base = (char*)d_ws;
    auto alloc = [&](size_t bytes) {
        char* p = base;
        base += (bytes + 255) & ~(size_t)255;
        return p;
    };
    float*    dis  = (float*)alloc((size_t)N_NODES * 4);
    int*      off  = (int*)alloc((size_t)(N_NODES + 1) * 4);
    int*      bfill= (int*)alloc((size_t)NBUCK * 4);
    unsigned* tmp  = (unsigned*)alloc((size_t)NBUCK * BCAP * 4 + 4096);
    unsigned* srt  = (unsigned*)alloc((size_t)N_EDGES * 4);
    f16*      m    = (f16*)alloc((size_t)N_NODES * 128 * 2);   // m1, reused as m2
    f16*      h1   = (f16*)alloc((size_t)N_NODES * 128 * 2);
    ushort_t* wt1h = (ushort_t*)alloc((size_t)128 * 192 * 2);
    ushort_t* wt1l = (ushort_t*)alloc((size_t)128 * 192 * 2);
    ushort_t* wt2h = (ushort_t*)alloc((size_t)64 * 128 * 2);
    ushort_t* wt2l = (ushort_t*)alloc((size_t)64 * 128 * 2);

    // wsplit + bfill zeroing (tiny)
    wsplit_kernel<<<WSPLIT_BLOCKS, 256, 0, stream>>>(W1, W2, wt1h, wt1l, wt2h, wt2l, bfill);

    // gemm1 (blocks 0..G1-1) || bucketA (last 256 blocks)
    bucketAg1_kernel<<<G1_BLOCKS + PA_BLOCKS, 256, 0, stream>>>(
        row, col, bfill, tmp, x, wt1h, wt1l, m, N_NODES);

    // bucketB: dis/off/srt
    bucketB_kernel<<<NBUCK, 256, 0, stream>>>(tmp, bfill, dis, off, srt);

    // layer 1 aggregation (dis applied per edge)
    agg1_kernel<<<(N_NODES + 3) / 4, 256, 0, stream>>>(m, srt, off, dis, b1, h1);

    // layer 2: m2 = h1 @ W2 (unscaled), then fused agg + output GEMM
    gemm2_kernel<<<G1_BLOCKS, 256, 0, stream>>>(h1, wt2h, wt2l, m, N_NODES);
    agg2_kernel<<<(N_NODES + 3) / 4, 256, 0, stream>>>(m, srt, off, dis, b2, Wo, bo, out);
}

// Round 21
// 194.997 us; speedup vs baseline: 1.0456x; 1.0456x over previous
//
#include <hip/hip_runtime.h>

#define N_NODES 100000
#define N_EDGES 1600000
#define IN_CH   165
#define BSHIFT 7
#define NBUCK  ((N_NODES + 127) / 128)   // 782
#define BCAP   3072                       // bucket region capacity (mean 2046, ~20 sigma)
#define PA_BLOCKS 256
#define WSPLIT_BLOCKS 128                 // (128*192 + 64*128) / 256 = 128
#define G1_BLOCKS ((N_NODES + 63) / 64)   // 1563

typedef unsigned short ushort_t;
typedef _Float16 f16;
typedef _Float16 f16x8 __attribute__((ext_vector_type(8)));
typedef _Float16 hfrag8 __attribute__((ext_vector_type(8)));
typedef short bfrag8 __attribute__((ext_vector_type(8)));   // 8 bf16 (4 VGPRs)
typedef float f32x4 __attribute__((ext_vector_type(4)));
typedef float f32x4u __attribute__((ext_vector_type(4), aligned(4)));  // 4B-aligned vector load

// bf16 round-to-nearest-even
__device__ __forceinline__ ushort_t f2bf(float f) {
    unsigned u = __float_as_uint(f);
    unsigned r = (u + 0x7fffu + ((u >> 16) & 1u)) >> 16;
    return (ushort_t)r;
}
__device__ __forceinline__ float bf2f(ushort_t h) {
    return __uint_as_float(((unsigned)h) << 16);
}

// acc += f16(half of pair) * s via v_fma_mix_f32
__device__ __forceinline__ void fmix_lo(float& a, unsigned pair, float s) {
    asm("v_fma_mix_f32 %0, %1, %2, %0 op_sel_hi:[1,0,0]" : "+v"(a) : "v"(pair), "v"(s));
}
__device__ __forceinline__ void fmix_hi(float& a, unsigned pair, float s) {
    asm("v_fma_mix_f32 %0, %1, %2, %0 op_sel:[1,0,0] op_sel_hi:[1,0,0]" : "+v"(a) : "v"(pair), "v"(s));
}
__device__ __forceinline__ void fmix_acc8(float* acc, uint4 v, float s) {
    fmix_lo(acc[0], v.x, s); fmix_hi(acc[1], v.x, s);
    fmix_lo(acc[2], v.y, s); fmix_hi(acc[3], v.y, s);
    fmix_lo(acc[4], v.z, s); fmix_hi(acc[5], v.z, s);
    fmix_lo(acc[6], v.w, s); fmix_hi(acc[7], v.w, s);
}

// ---------------- wsplit (also zeroes bfill) ----------------
// W1 -> bf16 hi/lo [ch][192]; W2 -> fp16 hi/lo [ch][128]
__global__ void wsplit_kernel(const float* __restrict__ W1, const float* __restrict__ W2,
                              ushort_t* __restrict__ wt1h, ushort_t* __restrict__ wt1l,
                              ushort_t* __restrict__ wt2h, ushort_t* __restrict__ wt2l,
                              int* __restrict__ bfill) {
    int i = blockIdx.x * 256 + threadIdx.x;
    if (i < NBUCK) bfill[i] = 0;
    if (i < 128 * 192) {
        int ch = i / 192, k = i - ch * 192;
        float v = (k < IN_CH) ? W1[(size_t)k * 128 + ch] : 0.f;
        ushort_t h = f2bf(v);
        wt1h[i] = h;
        wt1l[i] = f2bf(v - bf2f(h));
    } else if (i < 128 * 192 + 64 * 128) {
        int j = i - 128 * 192;
        int ch = j / 128, k = j - ch * 128;
        float v = W2[(size_t)k * 64 + ch];
        f16 h = (f16)v;
        f16 l = (f16)(v - (float)h);
        wt2h[j] = *(ushort_t*)&h;
        wt2l[j] = *(ushort_t*)&l;
    }
}

// ---------------- bucketAg1: bucketA (blocks 0..PA-1)  ||  gemm1 (rest) ----------
// bucketA: coarse scatter into fixed bucket regions tmp[b*BCAP..].
// gemm1: M[n][128] = X[n][165] @ W1 (UNSCALED), split-bf16 3-term MFMA, fp16 out.
//        W staged in LDS (cross-lane dedup, 20.5KB); X A-frags per-lane, float4x2.
__launch_bounds__(256)
__global__ void bucketAg1_kernel(const int* __restrict__ row, const int* __restrict__ col,
                                 int* __restrict__ bfill, unsigned* __restrict__ tmp,
                                 const float* __restrict__ X,
                                 const ushort_t* __restrict__ wth, const ushort_t* __restrict__ wtl,
                                 f16* __restrict__ M, int n_nodes) {
    __shared__ char smem[20480];
    int t = threadIdx.x;
    int lane = t & 63, wid = t >> 6;
    if (blockIdx.x < PA_BLOCKS) {
        // ---- bucketA ----
        int* lcnt = (int*)smem;                       // NBUCK ints
        int* lcur = ((int*)smem) + NBUCK;             // NBUCK ints (6256 B total)
        int e0 = (int)((long)blockIdx.x * N_EDGES / PA_BLOCKS);
        int e1 = (int)((long)(blockIdx.x + 1) * N_EDGES / PA_BLOCKS);
        for (int i = t; i < NBUCK; i += 256) lcnt[i] = 0;
        __syncthreads();
        for (int e = e0 + t; e < e1; e += 256)
            atomicAdd(&lcnt[col[e] >> BSHIFT], 1);
        __syncthreads();
        for (int b = t; b < NBUCK; b += 256) {
            int c = lcnt[b];
            lcur[b] = (c > 0) ? (b * BCAP + atomicAdd(&bfill[b], c)) : 0;
        }
        __syncthreads();
        for (int e = e0 + t; e < e1; e += 256) {
            int cc = col[e];
            int b = cc >> BSHIFT;
            int p = atomicAdd(&lcur[b], 1);
            tmp[p] = ((unsigned)(cc & 127) << 17) | (unsigned)row[e];
        }
        return;
    }
    // ---- gemm1: W in LDS, X per-lane (vectorized) ----
    constexpr int XP = 40;
    ushort_t (*wsh)[XP] = (ushort_t(*)[XP])smem;             // 10240
    ushort_t (*wsl)[XP] = (ushort_t(*)[XP])(smem + 10240);   // 10240

    int bid = blockIdx.x - PA_BLOCKS;
    long node0 = (long)bid * 64;
    int r = (int)node0 + wid * 16 + (lane & 15);
    int rr = min(r, n_nodes - 1);
    int q = lane >> 4;
    const float* xrow = X + (size_t)rr * IN_CH;

    f32x4 acc[8];
    #pragma unroll
    for (int ct = 0; ct < 8; ++ct) acc[ct] = (f32x4){0.f, 0.f, 0.f, 0.f};

    bfrag8 wfh[2], wfl[2];
    float a[8];

    auto loadW = [&](int c) {
        int k0 = c * 32;
        #pragma unroll
        for (int i = 0; i < 2; ++i) {
            int idx = t + i * 256;
            int ch = idx >> 2, qq = idx & 3;
            wfh[i] = *(const bfrag8*)&wth[(size_t)ch * 192 + k0 + qq * 8];
            wfl[i] = *(const bfrag8*)&wtl[(size_t)ch * 192 + k0 + qq * 8];
        }
    };
    auto storeW = [&]() {
        #pragma unroll
        for (int i = 0; i < 2; ++i) {
            int idx = t + i * 256;
            int ch = idx >> 2, qq = idx & 3;
            *(bfrag8*)&wsh[ch][qq * 8] = wfh[i];
            *(bfrag8*)&wsl[ch][qq * 8] = wfl[i];
        }
    };
    auto loadX = [&](int c) {
        int k = c * 32 + q * 8;
        if (c < 5) {
            f32x4u u = *(const f32x4u*)&xrow[k];
            f32x4u v = *(const f32x4u*)&xrow[k + 4];
            a[0] = u.x; a[1] = u.y; a[2] = u.z; a[3] = u.w;
            a[4] = v.x; a[5] = v.y; a[6] = v.z; a[7] = v.w;
        } else {
            // chunk 5: k in [160,192); valid only k<165 (quarter 0, elems 0..4)
            #pragma unroll
            for (int i = 0; i < 8; ++i) a[i] = 0.f;
            if (q == 0) {
                f32x4u u = *(const f32x4u*)&xrow[160];
                a[0] = u.x; a[1] = u.y; a[2] = u.z; a[3] = u.w;
                a[4] = xrow[164];
            }
        }
    };

    loadW(0);
    loadX(0);
    #pragma unroll 1
    for (int c = 0; c < 6; ++c) {
        storeW();
        __syncthreads();
        if (c + 1 < 6) loadW(c + 1);
        bfrag8 ah, al;
        #pragma unroll
        for (int i = 0; i < 8; ++i) {
            ushort_t h = (ushort_t)(__float_as_uint(a[i]) >> 16);   // truncation split
            ah[i] = (short)h;
            al[i] = (short)f2bf(a[i] - bf2f(h));
        }
        if (c + 1 < 6) loadX(c + 1);   // prefetch next A under MFMAs
        #pragma unroll
        for (int ct = 0; ct < 8; ++ct) {
            bfrag8 bh = *(const bfrag8*)&wsh[ct * 16 + (lane & 15)][q * 8];
            bfrag8 bl = *(const bfrag8*)&wsl[ct * 16 + (lane & 15)][q * 8];
            acc[ct] = __builtin_amdgcn_mfma_f32_16x16x32_bf16(ah, bh, acc[ct], 0, 0, 0);
            acc[ct] = __builtin_amdgcn_mfma_f32_16x16x32_bf16(ah, bl, acc[ct], 0, 0, 0);
            acc[ct] = __builtin_amdgcn_mfma_f32_16x16x32_bf16(al, bh, acc[ct], 0, 0, 0);
        }
        __syncthreads();
    }

    int nl = wid * 16 + (lane >> 4) * 4;
    #pragma unroll
    for (int ct = 0; ct < 8; ++ct) {
        int ch = ct * 16 + (lane & 15);
        #pragma unroll
        for (int j = 0; j < 4; ++j) {
            long node = node0 + nl + j;
            if (node < n_nodes)
                M[node * 128 + ch] = (f16)acc[ct][j];
        }
    }
}

// ---------------- bucketB: self-sufficient (recount, reduce base, dis/off/srt) ----
__global__ void bucketB_kernel(const unsigned* __restrict__ tmp, const int* __restrict__ bfill,
                               float* __restrict__ dis, int* __restrict__ off,
                               unsigned* __restrict__ srt) {
    __shared__ int lcnt[128];
    __shared__ int wred[4];
    __shared__ int sh[128];
    __shared__ int lcur[128];
    int t = threadIdx.x;
    int lane = t & 63, wid = t >> 6;
    int b = blockIdx.x;
    if (t < 128) lcnt[t] = 0;
    __syncthreads();
    int total = min(bfill[b], BCAP);
    const unsigned* reg = tmp + (size_t)b * BCAP;
    for (int i = t; i < total; i += 256)
        atomicAdd(&lcnt[(reg[i] >> 17) & 127], 1);
    // base = sum_{j<b} bfill[j]   (<=781 ints, L2-hot)
    int s = 0;
    for (int j = t; j < b; j += 256) s += bfill[j];
    #pragma unroll
    for (int o = 32; o > 0; o >>= 1) s += __shfl_xor(s, o);
    if (lane == 0) wred[wid] = s;
    __syncthreads();                       // fences lcnt atomics + wred
    int base = wred[0] + wred[1] + wred[2] + wred[3];
    int myc = 0;
    if (t < 128) {
        myc = lcnt[t];
        int n = (b << BSHIFT) + t;
        if (n < N_NODES) dis[n] = rsqrtf((float)(myc + 1));
        sh[t] = myc;
    }
    __syncthreads();
    for (int o = 1; o < 128; o <<= 1) {
        int x = (t < 128 && t >= o) ? sh[t - o] : 0;
        __syncthreads();
        if (t < 128) sh[t] += x;
        __syncthreads();
    }
    if (t < 128) {
        int excl = sh[t] - myc;
        int n = (b << BSHIFT) + t;
        if (n < N_NODES) off[n] = base + excl;
        lcur[t] = excl;
    }
    if (b == 0 && t == 0) off[N_NODES] = N_EDGES;
    __syncthreads();
    for (int i = t; i < total; i += 256) {
        unsigned e = reg[i];
        int c = (e >> 17) & 127;
        int p = atomicAdd(&lcur[c], 1);
        srt[base + p] = e & 0x1FFFFu;
    }
}

// ---------------- gemm2: M[n][64] = H[n][128] @ W2 (UNSCALED) ----------------
__launch_bounds__(256)
__global__ void gemm2_kernel(const f16* __restrict__ H,
                             const ushort_t* __restrict__ wth, const ushort_t* __restrict__ wtl,
                             f16* __restrict__ M, int n_nodes) {
    constexpr int XP = 40;
    __shared__ ushort_t wsh[64][XP];
    __shared__ ushort_t wsl[64][XP];
    int t = threadIdx.x;
    int l = t & 63, wid = t >> 6;
    long node0 = (long)blockIdx.x * 64;
    int r = (int)node0 + wid * 16 + (l & 15);
    int rr = min(r, n_nodes - 1);
    int q = l >> 4;
    const f16* hrow = H + (size_t)rr * 128;

    f32x4 acc[4];
    #pragma unroll
    for (int ct = 0; ct < 4; ++ct) acc[ct] = (f32x4){0.f, 0.f, 0.f, 0.f};

    bfrag8 wfh, wfl;
    auto loadW = [&](int c) {
        int ch = t >> 2, qq = t & 3;
        wfh = *(const bfrag8*)&wth[(size_t)ch * 128 + c * 32 + qq * 8];
        wfl = *(const bfrag8*)&wtl[(size_t)ch * 128 + c * 32 + qq * 8];
    };
    auto storeW = [&]() {
        int ch = t >> 2, qq = t & 3;
        *(bfrag8*)&wsh[ch][qq * 8] = wfh;
        *(bfrag8*)&wsl[ch][qq * 8] = wfl;
    };

    loadW(0);
    hfrag8 a = *(const hfrag8*)&hrow[q * 8];
    #pragma unroll 1
    for (int c = 0; c < 4; ++c) {
        storeW();
        __syncthreads();
        if (c + 1 < 4) loadW(c + 1);
        hfrag8 acur = a;
        if (c + 1 < 4) a = *(const hfrag8*)&hrow[(c + 1) * 32 + q * 8];
        #pragma unroll
        for (int ct = 0; ct < 4; ++ct) {
            hfrag8 bh = *(const hfrag8*)&wsh[ct * 16 + (l & 15)][q * 8];
            hfrag8 bl = *(const hfrag8*)&wsl[ct * 16 + (l & 15)][q * 8];
            acc[ct] = __builtin_amdgcn_mfma_f32_16x16x32_f16(acur, bh, acc[ct], 0, 0, 0);
            acc[ct] = __builtin_amdgcn_mfma_f32_16x16x32_f16(acur, bl, acc[ct], 0, 0, 0);
        }
        __syncthreads();
    }

    int nl = wid * 16 + (l >> 4) * 4;
    #pragma unroll
    for (int ct = 0; ct < 4; ++ct) {
        int ch = ct * 16 + (l & 15);
        #pragma unroll
        for (int j = 0; j < 4; ++j) {
            long node = node0 + nl + j;
            if (node < n_nodes)
                M[node * 64 + ch] = (f16)acc[ct][j];
        }
    }
}

// ---------------- aggregation layer 1: 128 ch fp16, wave-per-node ----------------
// srt plain src; dis[src] loaded per edge (L2-resident 400 KB); dn from degree.
__global__ void agg1_kernel(const f16* __restrict__ ms, const unsigned* __restrict__ srt,
                            const int* __restrict__ off, const float* __restrict__ dis,
                            const float* __restrict__ b1, f16* __restrict__ h1) {
    int wave = threadIdx.x >> 6;
    int lane = threadIdx.x & 63;
    int n = blockIdx.x * 4 + wave;
    if (n >= N_NODES) return;
    int g = lane >> 4, p = lane & 15;
    const char* msb = (const char*)ms;
    unsigned pb = (unsigned)p * 16;
    int s0 = off[n], s1 = off[n + 1];
    float dn = rsqrtf((float)(s1 - s0) + 1.f);
    float acc[8] = {0.f, 0.f, 0.f, 0.f, 0.f, 0.f, 0.f, 0.f};
    if (g == 0) {   // self row x dn
        uint4 v = *(const uint4*)(msb + (unsigned)n * 256 + pb);
        fmix_acc8(acc, v, dn);
    }
    unsigned sv = (s0 + lane < s1) ? srt[s0 + lane] : 0;
    for (int base = s0; base < s1; base += 64) {
        int nb2 = base + 64;
        unsigned svn = (nb2 + lane < s1) ? srt[nb2 + lane] : 0;
        int cnt_ = min(64, s1 - base);
        int j = 0;
        for (; j + 15 < cnt_; j += 16) {
            unsigned e0 = (unsigned)__shfl((int)sv, j + g);
            unsigned e1 = (unsigned)__shfl((int)sv, j + 4 + g);
            unsigned e2 = (unsigned)__shfl((int)sv, j + 8 + g);
            unsigned e3 = (unsigned)__shfl((int)sv, j + 12 + g);
            uint4 v0 = *(const uint4*)(msb + e0 * 256 + pb);
            uint4 v1 = *(const uint4*)(msb + e1 * 256 + pb);
            uint4 v2 = *(const uint4*)(msb + e2 * 256 + pb);
            uint4 v3 = *(const uint4*)(msb + e3 * 256 + pb);
            float d0 = dis[e0];
            float d1 = dis[e1];
            float d2 = dis[e2];
            float d3 = dis[e3];
            fmix_acc8(acc, v0, d0);
            fmix_acc8(acc, v1, d1);
            fmix_acc8(acc, v2, d2);
            fmix_acc8(acc, v3, d3);
        }
        for (; j < cnt_; j += 4) {
            unsigned e = (unsigned)__shfl((int)sv, j + g);
            float ws = (j + g < cnt_) ? dis[e] : 0.f;
            uint4 v = *(const uint4*)(msb + e * 256 + pb);
            fmix_acc8(acc, v, ws);
        }
        sv = svn;
    }
    #pragma unroll
    for (int i = 0; i < 8; ++i) {
        acc[i] += __shfl_xor(acc[i], 16);
        acc[i] += __shfl_xor(acc[i], 32);
    }
    if (lane < 16) {
        float4 ba = ((const float4*)b1)[lane * 2];
        float4 bb = ((const float4*)b1)[lane * 2 + 1];
        float bv[8] = {ba.x, ba.y, ba.z, ba.w, bb.x, bb.y, bb.z, bb.w};
        f16x8 r;
        #pragma unroll
        for (int i = 0; i < 8; ++i)
            r[i] = (f16)fmaxf(acc[i] * dn + bv[i], 0.f);
        *(f16x8*)(h1 + (size_t)n * 128 + lane * 8) = r;
    }
}

// ---------------- aggregation layer 2 (64 ch fp16) + output GEMM (64 -> 2) ----------------
__global__ void agg2_kernel(const f16* __restrict__ ms, const unsigned* __restrict__ srt,
                            const int* __restrict__ off, const float* __restrict__ dis,
                            const float* __restrict__ b2, const float* __restrict__ Wo,
                            const float* __restrict__ bo, float* __restrict__ out) {
    int wave = threadIdx.x >> 6;
    int lane = threadIdx.x & 63;
    int n = blockIdx.x * 4 + wave;
    if (n >= N_NODES) return;
    int g = lane >> 3, p = lane & 7;
    const char* msb = (const char*)ms;
    unsigned pb = (unsigned)p * 16;
    int s0 = off[n], s1 = off[n + 1];
    float dn = rsqrtf((float)(s1 - s0) + 1.f);
    float acc[8] = {0.f, 0.f, 0.f, 0.f, 0.f, 0.f, 0.f, 0.f};
    if (g == 0) {   // self row x dn
        uint4 v = *(const uint4*)(msb + (unsigned)n * 128 + pb);
        fmix_acc8(acc, v, dn);
    }
    unsigned sv = (s0 + lane < s1) ? srt[s0 + lane] : 0;
    for (int base = s0; base < s1; base += 64) {
        int nb2 = base + 64;
        unsigned svn = (nb2 + lane < s1) ? srt[nb2 + lane] : 0;
        int cnt_ = min(64, s1 - base);
        int j = 0;
        for (; j + 15 < cnt_; j += 16) {
            unsigned e0 = (unsigned)__shfl((int)sv, j + g);
            unsigned e1 = (unsigned)__shfl((int)sv, j + 8 + g);
            uint4 v0 = *(const uint4*)(msb + e0 * 128 + pb);
            uint4 v1 = *(const uint4*)(msb + e1 * 128 + pb);
            float d0 = dis[e0];
            float d1 = dis[e1];
            fmix_acc8(acc, v0, d0);
            fmix_acc8(acc, v1, d1);
        }
        for (; j < cnt_; j += 8) {
            unsigned e = (unsigned)__shfl((int)sv, j + g);
            float ws = (j + g < cnt_) ? dis[e] : 0.f;
            uint4 v = *(const uint4*)(msb + e * 128 + pb);
            fmix_acc8(acc, v, ws);
        }
        sv = svn;
    }
    #pragma unroll
    for (int i = 0; i < 8; ++i) {
        acc[i] += __shfl_xor(acc[i], 8);
        acc[i] += __shfl_xor(acc[i], 16);
        acc[i] += __shfl_xor(acc[i], 32);
    }
    float p0 = 0.f, p1 = 0.f;
    #pragma unroll
    for (int i = 0; i < 8; ++i) {
        int ch = p * 8 + i;
        float hc = fmaxf(acc[i] * dn + b2[ch], 0.f);
        p0 = fmaf(hc, Wo[ch * 2], p0);
        p1 = fmaf(hc, Wo[ch * 2 + 1], p1);
    }
    p0 += __shfl_xor(p0, 1); p1 += __shfl_xor(p1, 1);
    p0 += __shfl_xor(p0, 2); p1 += __shfl_xor(p1, 2);
    p0 += __shfl_xor(p0, 4); p1 += __shfl_xor(p1, 4);
    if (lane == 0) {
        out[(size_t)n * 2]     = p0 + bo[0];
        out[(size_t)n * 2 + 1] = p1 + bo[1];
    }
}

// ---------------- launch ----------------
extern "C" void kernel_launch(void* const* d_in, const int* in_sizes, int n_in,
                              void* d_out, int out_size, void* d_ws, size_t ws_size,
                              hipStream_t stream) {
    const float* x  = (const float*)d_in[0];
    const int*   ei = (const int*)d_in[1];
    const int*   row = ei;
    const int*   col = ei + N_EDGES;
    const float* W1 = (const float*)d_in[2];
    const float* b1 = (const float*)d_in[3];
    const float* W2 = (const float*)d_in[4];
    const float* b2 = (const float*)d_in[5];
    const float* Wo = (const float*)d_in[6];
    const float* bo = (const float*)d_in[7];
    float* out = (float*)d_out;

    char* base = (char*)d_ws;
    auto alloc = [&](size_t bytes) {
        char* p = base;
        base += (bytes + 255) & ~(size_t)255;
        return p;
    };
    float*    dis  = (float*)alloc((size_t)N_NODES * 4);
    int*      off  = (int*)alloc((size_t)(N_NODES + 1) * 4);
    int*      bfill= (int*)alloc((size_t)NBUCK * 4);
    unsigned* tmp  = (unsigned*)alloc((size_t)NBUCK * BCAP * 4 + 4096);
    unsigned* srt  = (unsigned*)alloc((size_t)N_EDGES * 4);
    f16*      m    = (f16*)alloc((size_t)N_NODES * 128 * 2);   // m1, reused as m2
    f16*      h1   = (f16*)alloc((size_t)N_NODES * 128 * 2);
    ushort_t* wt1h = (ushort_t*)alloc((size_t)128 * 192 * 2);
    ushort_t* wt1l = (ushort_t*)alloc((size_t)128 * 192 * 2);
    ushort_t* wt2h = (ushort_t*)alloc((size_t)64 * 128 * 2);
    ushort_t* wt2l = (ushort_t*)alloc((size_t)64 * 128 * 2);

    // wsplit + bfill zeroing (tiny)
    wsplit_kernel<<<WSPLIT_BLOCKS, 256, 0, stream>>>(W1, W2, wt1h, wt1l, wt2h, wt2l, bfill);

    // bucketA || gemm1 (both 20.5KB-LDS class -> co-resident)
    bucketAg1_kernel<<<PA_BLOCKS + G1_BLOCKS, 256, 0, stream>>>(
        row, col, bfill, tmp, x, wt1h, wt1l, m, N_NODES);

    // bucketB: dis/off/srt
    bucketB_kernel<<<NBUCK, 256, 0, stream>>>(tmp, bfill, dis, off, srt);

    // layer 1 aggregation (dis applied per edge)
    agg1_kernel<<<(N_NODES + 3) / 4, 256, 0, stream>>>(m, srt, off, dis, b1, h1);

    // layer 2: m2 = h1 @ W2 (unscaled), then fused agg + output GEMM
    gemm2_kernel<<<G1_BLOCKS, 256, 0, stream>>>(h1, wt2h, wt2l, m, N_NODES);
    agg2_kernel<<<(N_NODES + 3) / 4, 256, 0, stream>>>(m, srt, off, dis, b2, Wo, bo, out);
}